// Round 19
// baseline (50.086 us; speedup 1.0000x reference)
//
#include <hip/hip_runtime.h>
#include <math.h>

#define TOK 12544   // B*H*W
#define CDIM 128
#define NHEAD 4
#define HD 32
#define KS 7
#define HSZ 56
#define WSZ 56

typedef __attribute__((ext_vector_type(8))) short short8;   // bf16x8 mfma frag
typedef __attribute__((ext_vector_type(4))) float f32x4;

__device__ inline uint f2b(float f) {                        // fp32 -> bf16 RNE
    uint u = __float_as_uint(f);
    u += 0x7fffu + ((u >> 16) & 1u);
    return u >> 16;
}
__device__ inline float b2f(ushort u) { return __uint_as_float((uint)u << 16); }

// ---------- fragment-order weight conversion unit (R15-validated layout) ----------
// unit lu within a segment of row-len K: lr = lu&15, kg = (lu>>4)&3,
// k0g = (lu>>6)%(K/32), ngrp = (lu>>6)/(K/32); elems (n=ngrp*16+lr, k=k0g*32+kg*8+..)
__device__ inline void convert_unit(const float* __restrict__ src, int K, int lu,
                                    ushort* __restrict__ dst) {
    int lr = lu & 15;
    int t  = lu >> 4;
    int kg = t & 3; t >>= 2;
    int kk32 = K >> 5;
    int k0g = t % kk32;
    int ngrp = t / kk32;
    const float* s = src + (size_t)(ngrp * 16 + lr) * K + k0g * 32 + kg * 8;
    float4 v0 = *(const float4*)s;
    float4 v1 = *(const float4*)(s + 4);
    uint4 pk;
    pk.x = f2b(v0.x) | (f2b(v0.y) << 16);
    pk.y = f2b(v0.z) | (f2b(v0.w) << 16);
    pk.z = f2b(v1.x) | (f2b(v1.y) << 16);
    pk.w = f2b(v1.z) | (f2b(v1.w) << 16);
    *(uint4*)(dst + (size_t)lu * 8) = pk;
}

// ---------- convert ONLY the qkv weights (needed by ln1_qkv), 24 blocks ----------
__global__ void convert_qkv(const float* __restrict__ a, ushort* __restrict__ wb) {
    int u = blockIdx.x * 256 + threadIdx.x;    // 0..6143
    convert_unit(a, 128, u, wb);
}

// ---------- helper: LN of a 64-row tile into swizzled LDS (bf16), 8 waves ----------
__device__ inline void ln_to_lds(const float* __restrict__ X, int m0,
                                 const float* __restrict__ lnw, const float* __restrict__ lnb,
                                 ushort* __restrict__ lds) {
    int wv = threadIdx.x >> 6, lane = threadIdx.x & 63;
    #pragma unroll
    for (int r = 0; r < 8; r++) {
        int rl = wv * 8 + r;
        float2 v = *(const float2*)(X + (size_t)(m0 + rl) * CDIM + lane * 2);
        float s  = v.x + v.y;
        float s2 = v.x * v.x + v.y * v.y;
        #pragma unroll
        for (int o = 32; o > 0; o >>= 1) {
            s  += __shfl_xor(s, o);
            s2 += __shfl_xor(s2, o);
        }
        float mu = s * (1.0f / 128.0f);
        float var = s2 * (1.0f / 128.0f) - mu * mu;
        float rstd = rsqrtf(var + 1e-5f);
        float d0 = v.x - mu, d1 = v.y - mu;
        float2 wv2 = *(const float2*)(lnw + lane * 2);
        float2 bv2 = *(const float2*)(lnb + lane * 2);
        uint pk = f2b(d0 * rstd * wv2.x + bv2.x)
                | (f2b(d1 * rstd * wv2.y + bv2.y) << 16);
        *(uint*)((char*)lds + rl * 256 + ((lane * 4) ^ ((rl & 7) << 4))) = pk;
    }
}

// ---------- fused LN1 + QKV GEMM (R17/R18-validated) ----------
__global__ __launch_bounds__(512) void ln1_qkv(const float* __restrict__ X,
                                               const ushort* __restrict__ W,
                                               const float* __restrict__ bias,
                                               const float* __restrict__ lnw,
                                               const float* __restrict__ lnb,
                                               ushort* __restrict__ Y) {
    __shared__ ushort xn[64 * 128];   // 16 KB swizzled (LN input tile)
    __shared__ ushort yb[64 * 384];   // 48 KB output stage, row-XOR swizzled
    int m0 = blockIdx.x * 64;
    int tid = threadIdx.x;
    int wv = tid >> 6, lane = tid & 63;
    int lr = lane & 15, kg = lane >> 4;

    // preload k0=0 B-frags (independent of LDS; hides W L2 latency under LN)
    short8 bf0[3];
    #pragma unroll
    for (int ni = 0; ni < 3; ni++)
        bf0[ni] = *(const short8*)(W + (size_t)(((((wv * 3 + ni) * 4 + 0) * 4 + kg) * 16 + lr)) * 8);

    ln_to_lds(X, m0, lnw, lnb, xn);
    __syncthreads();

    int n0 = wv * 48;
    f32x4 acc[4][3] = {};
    #pragma unroll
    for (int k0 = 0; k0 < 128; k0 += 32) {
        short8 bf[3];
        #pragma unroll
        for (int ni = 0; ni < 3; ni++)
            bf[ni] = (k0 == 0) ? bf0[ni]
                   : *(const short8*)(W + (size_t)(((((wv * 3 + ni) * 4 + (k0 >> 5)) * 4 + kg) * 16 + lr)) * 8);
        #pragma unroll
        for (int mg = 0; mg < 4; mg++) {
            int row = mg * 16 + lr;
            short8 a0 = *(const short8*)((char*)xn + row * 256 + ((k0 * 2 + kg * 16) ^ ((row & 7) << 4)));
            #pragma unroll
            for (int ni = 0; ni < 3; ni++)
                acc[mg][ni] = __builtin_amdgcn_mfma_f32_16x16x32_bf16(a0, bf[ni], acc[mg][ni], 0, 0, 0);
        }
    }
    // ---- epilogue: bias+scale -> yb (swizzled), then coalesced head-major stores ----
    #pragma unroll
    for (int mg = 0; mg < 4; mg++)
    #pragma unroll
    for (int ni = 0; ni < 3; ni++) {
        int base = n0 + ni * 16;
        int col = base + lr;
        float bn = bias[col];
        float sc = (base < CDIM) ? 0.17677669529663687f : 1.0f;
        #pragma unroll
        for (int r = 0; r < 4; r++) {
            int row = mg * 16 + kg * 4 + r;
            float v = (acc[mg][ni][r] + bn) * sc;
            *(ushort*)((char*)yb + row * 768 + ((col * 2) ^ ((row & 15) << 4))) = (ushort)f2b(v);
        }
    }
    __syncthreads();
    #pragma unroll
    for (int it = 0; it < 6; it++) {
        int idx = it * 512 + tid;
        int which = idx >> 10;                 // 0=q 1=k 2=v
        int rem   = idx & 1023;
        int head  = rem >> 8;
        int hrow  = (rem >> 2) & 63;
        int sl    = rem & 3;
        int col   = which * 128 + head * 32 + sl * 8;
        short8 v = *(const short8*)((char*)yb + hrow * 768 + ((col * 2) ^ ((hrow & 15) << 4)));
        *(short8*)(Y + ((size_t)(which * 4 + head) * TOK + m0 + hrow) * HD + sl * 8) = v;
    }
}

// ---------- fused proj + LN2 + FC1/GELU + FC2 + residuals (R17/R18-validated) ----------
__global__ __launch_bounds__(512) void proj_mlp(const ushort* __restrict__ aob,
                                                const ushort* __restrict__ Wp,
                                                const float* __restrict__ bp,
                                                const float* __restrict__ X,
                                                const ushort* __restrict__ W1,
                                                const float* __restrict__ b1,
                                                const ushort* __restrict__ W2,
                                                const float* __restrict__ b2,
                                                const float* __restrict__ lnw,
                                                const float* __restrict__ lnb,
                                                float* __restrict__ out) {
    __shared__ float  x2f[64 * 132];  // stride 132: 2-way epilogue banking (free)
    __shared__ ushort zn[64 * 128];   // 16 KB swizzled
    __shared__ ushort hb[64 * 512];   // 64 KB swizzled; first 16KB aliased as A-stage
    int m0 = blockIdx.x * 64;
    int tid = threadIdx.x;
    int wv = tid >> 6, lane = tid & 63;
    int lr = lane & 15, kg = lane >> 4;

    // ---- hoisted residual loads (consumed in proj epilogue) ----
    float xres[4][4];
    {
        int n0 = wv * 16;
        #pragma unroll
        for (int mg = 0; mg < 4; mg++)
        #pragma unroll
        for (int r = 0; r < 4; r++)
            xres[mg][r] = X[(size_t)(m0 + mg * 16 + kg * 4 + r) * CDIM + n0 + lr];
    }

    // ---- stage aob tile (64x128 bf16) into hb, coalesced + swizzled ----
    #pragma unroll
    for (int it = 0; it < 2; it++) {
        int idx = it * 512 + tid;            // 1024 chunks of 16B
        int row = idx >> 4, sl = idx & 15;
        short8 v = *(const short8*)(aob + (size_t)(m0 + row) * 128 + sl * 8);
        *(short8*)((char*)hb + row * 256 + ((sl * 16) ^ ((row & 7) << 4))) = v;
    }
    __syncthreads();

    // ---- proj: wave w owns cols [w*16, +16) over all 64 rows (ngrp = wv) ----
    {
        int n0 = wv * 16;
        f32x4 accp[4] = {};
        #pragma unroll
        for (int k0 = 0; k0 < 128; k0 += 32) {
            short8 bf = *(const short8*)(Wp + (size_t)((((wv * 4 + (k0 >> 5)) * 4 + kg) * 16 + lr)) * 8);
            #pragma unroll
            for (int mg = 0; mg < 4; mg++) {
                int row = mg * 16 + lr;
                short8 a0 = *(const short8*)((char*)hb + row * 256 + ((k0 * 2 + kg * 16) ^ ((row & 7) << 4)));
                accp[mg] = __builtin_amdgcn_mfma_f32_16x16x32_bf16(a0, bf, accp[mg], 0, 0, 0);
            }
        }
        float bn = bp[n0 + lr];
        #pragma unroll
        for (int mg = 0; mg < 4; mg++)
        #pragma unroll
        for (int r = 0; r < 4; r++) {
            int row = mg * 16 + kg * 4 + r;
            x2f[row * 132 + n0 + lr] = accp[mg][r] + bn + xres[mg][r];
        }
    }
    __syncthreads();

    // ---- LN2 from x2f -> zn (swizzled bf16), concurrent reductions ----
    #pragma unroll
    for (int r = 0; r < 8; r++) {
        int rl = wv * 8 + r;
        float2 v = *(const float2*)&x2f[rl * 132 + lane * 2];
        float s  = v.x + v.y;
        float s2 = v.x * v.x + v.y * v.y;
        #pragma unroll
        for (int o = 32; o > 0; o >>= 1) {
            s  += __shfl_xor(s, o);
            s2 += __shfl_xor(s2, o);
        }
        float mu = s * (1.0f / 128.0f);
        float var = s2 * (1.0f / 128.0f) - mu * mu;
        float rstd = rsqrtf(var + 1e-5f);
        float d0 = v.x - mu, d1 = v.y - mu;
        float2 wv2 = *(const float2*)(lnw + lane * 2);
        float2 bv2 = *(const float2*)(lnb + lane * 2);
        uint pk = f2b(d0 * rstd * wv2.x + bv2.x)
                | (f2b(d1 * rstd * wv2.y + bv2.y) << 16);
        *(uint*)((char*)zn + rl * 256 + ((lane * 4) ^ ((rl & 7) << 4))) = pk;
    }
    __syncthreads();

    // ---- fc1 + GELU single pass: wave owns cols [wv*64, +64), ngrp = wv*4+ni ----
    {
        f32x4 acc1[4][4] = {};
        int nc0 = wv * 64;
        #pragma unroll
        for (int k0 = 0; k0 < 128; k0 += 32) {
            short8 bf[4];
            #pragma unroll
            for (int ni = 0; ni < 4; ni++)
                bf[ni] = *(const short8*)(W1 + (size_t)(((((wv * 4 + ni) * 4 + (k0 >> 5)) * 4 + kg) * 16 + lr)) * 8);
            #pragma unroll
            for (int mg = 0; mg < 4; mg++) {
                int row = mg * 16 + lr;
                short8 a0 = *(const short8*)((char*)zn + row * 256 + ((k0 * 2 + kg * 16) ^ ((row & 7) << 4)));
                #pragma unroll
                for (int ni = 0; ni < 4; ni++)
                    acc1[mg][ni] = __builtin_amdgcn_mfma_f32_16x16x32_bf16(a0, bf[ni], acc1[mg][ni], 0, 0, 0);
            }
        }
        #pragma unroll
        for (int mg = 0; mg < 4; mg++)
        #pragma unroll
        for (int ni = 0; ni < 4; ni++) {
            int lc = nc0 + ni * 16 + lr;
            float bn = b1[lc];
            #pragma unroll
            for (int r = 0; r < 4; r++) {
                int row = mg * 16 + kg * 4 + r;
                float v = acc1[mg][ni][r] + bn;
                // sigmoid-form tanh GELU (max dev ~3e-4 vs exact erf)
                float t = v + 0.044715f * v * v * v;
                float sg = 1.0f / (1.0f + __expf(-1.5957691216f * t));
                v = v * sg;
                *(ushort*)((char*)hb + row * 1024 + ((lc * 2) ^ ((row & 7) << 4))) = (ushort)f2b(v);
            }
        }
    }
    __syncthreads();

    // ---- fc2: unbroken K = 512 loop from hb; ngrp = (wv&3)*2+ni ----
    int rw0 = (wv >> 2) * 32, cw0 = (wv & 3) * 32;   // fc2 wave tile 32x32
    f32x4 acc2[2][2] = {};
    #pragma unroll
    for (int k0 = 0; k0 < 512; k0 += 32) {
        short8 a0[2], bf[2];
        #pragma unroll
        for (int mi = 0; mi < 2; mi++) {
            int row = rw0 + mi * 16 + lr;
            a0[mi] = *(const short8*)((char*)hb + row * 1024 + ((k0 * 2 + kg * 16) ^ ((row & 7) << 4)));
        }
        #pragma unroll
        for (int ni = 0; ni < 2; ni++)
            bf[ni] = *(const short8*)(W2 + (size_t)((((((wv & 3) * 2 + ni) * 16 + (k0 >> 5)) * 4 + kg) * 16 + lr)) * 8);
        #pragma unroll
        for (int mi = 0; mi < 2; mi++)
        #pragma unroll
        for (int ni = 0; ni < 2; ni++)
            acc2[mi][ni] = __builtin_amdgcn_mfma_f32_16x16x32_bf16(a0[mi], bf[ni], acc2[mi][ni], 0, 0, 0);
    }

    #pragma unroll
    for (int mi = 0; mi < 2; mi++)
    #pragma unroll
    for (int ni = 0; ni < 2; ni++) {
        int col = cw0 + ni * 16 + lr;
        float bn = b2[col];
        #pragma unroll
        for (int r = 0; r < 4; r++) {
            int row = rw0 + mi * 16 + kg * 4 + r;
            out[(size_t)(m0 + row) * CDIM + col] = acc2[mi][ni][r] + bn + x2f[row * 132 + col];
        }
    }
}

// ---------- Neighborhood attention v10: R18 attn + tail blocks convert proj/fc weights ----------
__global__ __launch_bounds__(256) void nat_attn10(const ushort* __restrict__ qkv,
                                                  const float* __restrict__ rpb,
                                                  ushort* __restrict__ ao,
                                                  const float* __restrict__ wpf,
                                                  const float* __restrict__ w1f,
                                                  const float* __restrict__ w2f,
                                                  ushort* __restrict__ wb) {
    int tid = threadIdx.x;
    int bid = blockIdx.x;
    if (bid >= 784) {
        // convert proj/fc1/fc2 weights (consumed by proj_mlp, which runs after us)
        int u = (bid - 784) * 256 + tid;       // 0..18431
        int e = 49152 + u * 8;
        if (e < 65536)       convert_unit(wpf, 128, (e - 49152) >> 3, wb + 49152);
        else if (e < 131072) convert_unit(w1f, 128, (e - 65536) >> 3, wb + 65536);
        else                 convert_unit(w2f, 512, (e - 131072) >> 3, wb + 131072);
        return;
    }

    __shared__ ushort katt[8704];      // union: ks[208*40]=8320 (scores) / att 4x16x136
    __shared__ ushort vs[32 * 232];
    __shared__ float rpl[169];
    ushort* ks = katt;

    int wv = tid >> 6, lane = tid & 63;
    int lr = lane & 15, kg = lane >> 4;
    int blk = (bid & 7) * 98 + (bid >> 3);   // bijective XCD chunking (784 = 8*98)
    int tile = blk % 49, hb2 = blk / 49;
    int head = hb2 & 3, b = hb2 >> 2;
    int r0 = (tile / 7) * 8, c0 = (tile % 7) * 8;
    int hr0 = min(max(r0 - 3, 0), HSZ - 14);
    int hc0 = min(max(c0 - 3, 0), WSZ - 14);
    int bimg = b * HSZ * WSZ;

    const ushort* qb = qkv + (size_t)(0 + head) * TOK * HD;
    const ushort* kb = qkv + (size_t)(4 + head) * TOK * HD;
    const ushort* vb = qkv + (size_t)(8 + head) * TOK * HD;

    // hoisted Q-frag load: issues alongside staging loads
    int apix = wv * 16 + lr;
    int agp = bimg + (r0 + 2 * wv + ((apix & 15) >> 3)) * WSZ + c0 + (apix & 7);
    short8 aq = *(const short8*)(qb + (size_t)agp * HD + kg * 8);

    if (tid < 169) rpl[tid] = rpb[head * 169 + tid];
    for (int idx = tid; idx < 784; idx += 256) {
        int t = idx >> 2, c = idx & 3;
        int gtok = bimg + (hr0 + t / 14) * WSZ + hc0 + t % 14;
        short8 v = *(const short8*)(kb + (size_t)gtok * HD + c * 8);
        *(short8*)(ks + t * 40 + c * 8) = v;
    }
    for (int idx = tid; idx < 392; idx += 256) {
        int pr = idx >> 2, c = idx & 3;
        int t = pr * 2;
        int gtok = bimg + (hr0 + t / 14) * WSZ + hc0 + t % 14;
        const ushort* vp = vb + (size_t)gtok * HD + c * 8;
        short8 v0 = *(const short8*)vp;
        short8 v1 = *(const short8*)(vp + HD);
        #pragma unroll
        for (int q = 0; q < 8; q++)
            *(uint*)(vs + (c * 8 + q) * 232 + t) =
                (uint)(ushort)v0[q] | ((uint)(ushort)v1[q] << 16);
    }
    for (int idx = tid; idx < 32 * 18; idx += 256)
        *(uint*)(vs + (idx / 18) * 232 + 196 + (idx % 18) * 2) = 0;
    __syncthreads();

    int i0 = r0 + 2 * wv;
    int hw0 = min(max(i0 - 3, 0), HSZ - KS);
    int dwr = hw0 - hr0;
    int tbase = dwr * 14;
    int rb = tbase & ~7;
    int rboff = tbase - rb;                  // even, in {0,2,4,6}

    f32x4 sc[7];
    #pragma unroll
    for (int tl = 0; tl < 7; tl++) {
        int t = tbase + tl * 16 + lr;
        short8 bk = *(const short8*)(ks + t * 40 + kg * 8);
        f32x4 z = {0.f, 0.f, 0.f, 0.f};
        sc[tl] = __builtin_amdgcn_mfma_f32_16x16x32_bf16(aq, bk, z, 0, 0, 0);
    }
    __syncthreads();   // all ks reads done before att overwrites the union

    ushort* attw = katt + wv * 16 * 136;
    #pragma unroll
    for (int z = 0; z < 2; z++) {
        int ii = z * 64 + lane;              // 0..127 pad-uints (16 rows x 8)
        int row = ii >> 3, c2 = (ii & 7) * 2;
        int col = c2 + (c2 < rboff ? 0 : 112);
        *(uint*)(attw + row * 136 + col) = 0;
    }

    float inv[4];
    #pragma unroll
    for (int r = 0; r < 4; r++) {
        int idx = kg * 4 + r;
        int i = r0 + 2 * wv + (idx >> 3), j = c0 + (idx & 7);
        int shh = min(max(i - 3, 0), HSZ - KS);
        int sww = min(max(j - 3, 0), WSZ - KS);
        int dih = shh - hr0, dj = sww - hc0;
        int offh = hr0 - i + 6, offw = hc0 - j + 6;
        float sum = 0.f;
        #pragma unroll
        for (int tl = 0; tl < 7; tl++) {
            int t = tbase + tl * 16 + lr;
            int thr = (unsigned)t / 14u;
            int twr = t - thr * 14;
            bool in = ((unsigned)(thr - dih) < 7u) && ((unsigned)(twr - dj) < 7u);
            int bidx = (thr + offh) * 13 + (twr + offw);
            bidx = min(max(bidx, 0), 168);
            float e = in ? __expf(sc[tl][r] + rpl[bidx]) : 0.f;
            sum += e;
            attw[idx * 136 + rboff + tl * 16 + lr] = (ushort)f2b(e);
        }
        #pragma unroll
        for (int o = 8; o > 0; o >>= 1) sum += __shfl_xor(sum, o);
        inv[r] = 1.0f / sum;
    }

    f32x4 po[2] = {};
    #pragma unroll
    for (int kst = 0; kst < 4; kst++) {
        short8 pa = *(const short8*)(attw + lr * 136 + kst * 32 + kg * 8);
        #pragma unroll
        for (int n = 0; n < 2; n++) {
            short8 vbf = *(const short8*)(vs + (n * 16 + lr) * 232 + rb + kst * 32 + kg * 8);
            po[n] = __builtin_amdgcn_mfma_f32_16x16x32_bf16(pa, vbf, po[n], 0, 0, 0);
        }
    }

    #pragma unroll
    for (int n = 0; n < 2; n++)
    #pragma unroll
    for (int rr = 0; rr < 4; rr++) {
        int idx = kg * 4 + rr;
        int gp = bimg + (r0 + 2 * wv + (idx >> 3)) * WSZ + c0 + (idx & 7);
        ao[(size_t)gp * CDIM + head * HD + n * 16 + lr] = (ushort)f2b(po[n][rr] * inv[rr]);
    }
}

extern "C" void kernel_launch(void* const* d_in, const int* in_sizes, int n_in,
                              void* d_out, int out_size, void* d_ws, size_t ws_size,
                              hipStream_t stream) {
    const float* x      = (const float*)d_in[0];
    const float* n1w    = (const float*)d_in[1];
    const float* n1b    = (const float*)d_in[2];
    const float* qkv_w  = (const float*)d_in[3];
    const float* qkv_b  = (const float*)d_in[4];
    const float* rpb    = (const float*)d_in[5];
    const float* proj_w = (const float*)d_in[6];
    const float* proj_b = (const float*)d_in[7];
    const float* n2w    = (const float*)d_in[8];
    const float* n2b    = (const float*)d_in[9];
    const float* fc1_w  = (const float*)d_in[10];
    const float* fc1_b  = (const float*)d_in[11];
    const float* fc2_w  = (const float*)d_in[12];
    const float* fc2_b  = (const float*)d_in[13];
    float* out = (float*)d_out;

    ushort* wb   = (ushort*)d_ws;                        // 196608 bf16 weights (frag order)
    ushort* qkvb = wb + 196608;                          // [3][4][TOK][32] bf16
    ushort* aob  = qkvb + (size_t)TOK * 384;             // TOK*128 bf16

    const ushort* w_qkv  = wb;
    const ushort* w_proj = wb + 49152;
    const ushort* w_fc1  = wb + 65536;
    const ushort* w_fc2  = wb + 131072;

    convert_qkv<<<24, 256, 0, stream>>>(qkv_w, wb);
    ln1_qkv<<<TOK / 64, 512, 0, stream>>>(x, w_qkv, qkv_b, n1w, n1b, qkvb);
    nat_attn10<<<784 + 72, 256, 0, stream>>>(qkvb, rpb, aob, proj_w, fc1_w, fc2_w, wb);
    proj_mlp<<<TOK / 64, 512, 0, stream>>>(aob, w_proj, proj_b, x,
                                           w_fc1, fc1_b, w_fc2, fc2_b, n2w, n2b, out);
}

// Round 20
// 49.373 us; speedup vs baseline: 1.0144x; 1.0144x over previous
//
#include <hip/hip_runtime.h>
#include <math.h>

#define TOK 12544   // B*H*W
#define CDIM 128
#define NHEAD 4
#define HD 32
#define KS 7
#define HSZ 56
#define WSZ 56

typedef __attribute__((ext_vector_type(8))) short short8;   // bf16x8 mfma frag
typedef __attribute__((ext_vector_type(4))) float f32x4;

__device__ inline uint f2b(float f) {                        // fp32 -> bf16 RNE
    uint u = __float_as_uint(f);
    u += 0x7fffu + ((u >> 16) & 1u);
    return u >> 16;
}
__device__ inline float b2f(ushort u) { return __uint_as_float((uint)u << 16); }

// ---------- convert weights to bf16 in MFMA FRAGMENT ORDER (R15-validated) ----------
__global__ void convert_w(const float* __restrict__ a, const float* __restrict__ b,
                          const float* __restrict__ c, const float* __restrict__ d,
                          ushort* __restrict__ wb) {
    int u = blockIdx.x * 256 + threadIdx.x;    // frag-row unit (8 elems)
    int e = u * 8;
    const float* src; int base, K;
    if (e < 49152)       { src = a; base = 0;      K = 128; }
    else if (e < 65536)  { src = b; base = 49152;  K = 128; }
    else if (e < 131072) { src = c; base = 65536;  K = 128; }
    else                 { src = d; base = 131072; K = 512; }
    int lu = (e - base) >> 3;
    int lr = lu & 15;
    int t  = lu >> 4;
    int kg = t & 3; t >>= 2;
    int kk32 = K >> 5;
    int k0g = t % kk32;
    int ngrp = t / kk32;
    const float* s = src + (size_t)(ngrp * 16 + lr) * K + k0g * 32 + kg * 8;
    float4 v0 = *(const float4*)s;
    float4 v1 = *(const float4*)(s + 4);
    uint4 pk;
    pk.x = f2b(v0.x) | (f2b(v0.y) << 16);
    pk.y = f2b(v0.z) | (f2b(v0.w) << 16);
    pk.z = f2b(v1.x) | (f2b(v1.y) << 16);
    pk.w = f2b(v1.z) | (f2b(v1.w) << 16);
    *(uint4*)(wb + base + (size_t)lu * 8) = pk;
}

// ---------- helper: LN of a 64-row tile into swizzled LDS (bf16), 8 waves ----------
__device__ inline void ln_to_lds(const float* __restrict__ X, int m0,
                                 const float* __restrict__ lnw, const float* __restrict__ lnb,
                                 ushort* __restrict__ lds) {
    int wv = threadIdx.x >> 6, lane = threadIdx.x & 63;
    #pragma unroll
    for (int r = 0; r < 8; r++) {
        int rl = wv * 8 + r;
        float2 v = *(const float2*)(X + (size_t)(m0 + rl) * CDIM + lane * 2);
        float s  = v.x + v.y;
        float s2 = v.x * v.x + v.y * v.y;
        #pragma unroll
        for (int o = 32; o > 0; o >>= 1) {
            s  += __shfl_xor(s, o);
            s2 += __shfl_xor(s2, o);
        }
        float mu = s * (1.0f / 128.0f);
        float var = s2 * (1.0f / 128.0f) - mu * mu;
        float rstd = rsqrtf(var + 1e-5f);
        float d0 = v.x - mu, d1 = v.y - mu;
        float2 wv2 = *(const float2*)(lnw + lane * 2);
        float2 bv2 = *(const float2*)(lnb + lane * 2);
        uint pk = f2b(d0 * rstd * wv2.x + bv2.x)
                | (f2b(d1 * rstd * wv2.y + bv2.y) << 16);
        *(uint*)((char*)lds + rl * 256 + ((lane * 4) ^ ((rl & 7) << 4))) = pk;
    }
}

// ---------- fused LN1 + QKV GEMM (R17/R18-validated) ----------
__global__ __launch_bounds__(512) void ln1_qkv(const float* __restrict__ X,
                                               const ushort* __restrict__ W,
                                               const float* __restrict__ bias,
                                               const float* __restrict__ lnw,
                                               const float* __restrict__ lnb,
                                               ushort* __restrict__ Y) {
    __shared__ ushort xn[64 * 128];   // 16 KB swizzled (LN input tile)
    __shared__ ushort yb[64 * 384];   // 48 KB output stage, row-XOR swizzled
    int m0 = blockIdx.x * 64;
    int tid = threadIdx.x;
    int wv = tid >> 6, lane = tid & 63;
    int lr = lane & 15, kg = lane >> 4;

    // preload k0=0 B-frags (independent of LDS; hides W L2 latency under LN)
    short8 bf0[3];
    #pragma unroll
    for (int ni = 0; ni < 3; ni++)
        bf0[ni] = *(const short8*)(W + (size_t)(((((wv * 3 + ni) * 4 + 0) * 4 + kg) * 16 + lr)) * 8);

    ln_to_lds(X, m0, lnw, lnb, xn);
    __syncthreads();

    int n0 = wv * 48;
    f32x4 acc[4][3] = {};
    #pragma unroll
    for (int k0 = 0; k0 < 128; k0 += 32) {
        short8 bf[3];
        #pragma unroll
        for (int ni = 0; ni < 3; ni++)
            bf[ni] = (k0 == 0) ? bf0[ni]
                   : *(const short8*)(W + (size_t)(((((wv * 3 + ni) * 4 + (k0 >> 5)) * 4 + kg) * 16 + lr)) * 8);
        #pragma unroll
        for (int mg = 0; mg < 4; mg++) {
            int row = mg * 16 + lr;
            short8 a0 = *(const short8*)((char*)xn + row * 256 + ((k0 * 2 + kg * 16) ^ ((row & 7) << 4)));
            #pragma unroll
            for (int ni = 0; ni < 3; ni++)
                acc[mg][ni] = __builtin_amdgcn_mfma_f32_16x16x32_bf16(a0, bf[ni], acc[mg][ni], 0, 0, 0);
        }
    }
    // ---- epilogue: bias+scale -> yb (swizzled), then coalesced head-major stores ----
    #pragma unroll
    for (int mg = 0; mg < 4; mg++)
    #pragma unroll
    for (int ni = 0; ni < 3; ni++) {
        int base = n0 + ni * 16;
        int col = base + lr;
        float bn = bias[col];
        float sc = (base < CDIM) ? 0.17677669529663687f : 1.0f;
        #pragma unroll
        for (int r = 0; r < 4; r++) {
            int row = mg * 16 + kg * 4 + r;
            float v = (acc[mg][ni][r] + bn) * sc;
            *(ushort*)((char*)yb + row * 768 + ((col * 2) ^ ((row & 15) << 4))) = (ushort)f2b(v);
        }
    }
    __syncthreads();
    #pragma unroll
    for (int it = 0; it < 6; it++) {
        int idx = it * 512 + tid;
        int which = idx >> 10;                 // 0=q 1=k 2=v
        int rem   = idx & 1023;
        int head  = rem >> 8;
        int hrow  = (rem >> 2) & 63;
        int sl    = rem & 3;
        int col   = which * 128 + head * 32 + sl * 8;
        short8 v = *(const short8*)((char*)yb + hrow * 768 + ((col * 2) ^ ((hrow & 15) << 4)));
        *(short8*)(Y + ((size_t)(which * 4 + head) * TOK + m0 + hrow) * HD + sl * 8) = v;
    }
}

// ---------- fused proj + LN2 + FC1/GELU + FC2 + residuals (R18 + W1 preload) ----------
__global__ __launch_bounds__(512) void proj_mlp(const ushort* __restrict__ aob,
                                                const ushort* __restrict__ Wp,
                                                const float* __restrict__ bp,
                                                const float* __restrict__ X,
                                                const ushort* __restrict__ W1,
                                                const float* __restrict__ b1,
                                                const ushort* __restrict__ W2,
                                                const float* __restrict__ b2,
                                                const float* __restrict__ lnw,
                                                const float* __restrict__ lnb,
                                                float* __restrict__ out) {
    __shared__ float  x2f[64 * 132];  // stride 132: 2-way epilogue banking (free)
    __shared__ ushort zn[64 * 128];   // 16 KB swizzled
    __shared__ ushort hb[64 * 512];   // 64 KB swizzled; first 16KB aliased as A-stage
    int m0 = blockIdx.x * 64;
    int tid = threadIdx.x;
    int wv = tid >> 6, lane = tid & 63;
    int lr = lane & 15, kg = lane >> 4;

    // ---- hoisted residual loads (consumed in proj epilogue) ----
    float xres[4][4];
    {
        int n0 = wv * 16;
        #pragma unroll
        for (int mg = 0; mg < 4; mg++)
        #pragma unroll
        for (int r = 0; r < 4; r++)
            xres[mg][r] = X[(size_t)(m0 + mg * 16 + kg * 4 + r) * CDIM + n0 + lr];
    }

    // ---- stage aob tile (64x128 bf16) into hb, coalesced + swizzled ----
    #pragma unroll
    for (int it = 0; it < 2; it++) {
        int idx = it * 512 + tid;            // 1024 chunks of 16B
        int row = idx >> 4, sl = idx & 15;
        short8 v = *(const short8*)(aob + (size_t)(m0 + row) * 128 + sl * 8);
        *(short8*)((char*)hb + row * 256 + ((sl * 16) ^ ((row & 7) << 4))) = v;
    }
    __syncthreads();

    // ---- proj: wave w owns cols [w*16, +16) over all 64 rows (ngrp = wv) ----
    {
        int n0 = wv * 16;
        f32x4 accp[4] = {};
        #pragma unroll
        for (int k0 = 0; k0 < 128; k0 += 32) {
            short8 bf = *(const short8*)(Wp + (size_t)((((wv * 4 + (k0 >> 5)) * 4 + kg) * 16 + lr)) * 8);
            #pragma unroll
            for (int mg = 0; mg < 4; mg++) {
                int row = mg * 16 + lr;
                short8 a0 = *(const short8*)((char*)hb + row * 256 + ((k0 * 2 + kg * 16) ^ ((row & 7) << 4)));
                accp[mg] = __builtin_amdgcn_mfma_f32_16x16x32_bf16(a0, bf, accp[mg], 0, 0, 0);
            }
        }
        float bn = bp[n0 + lr];
        #pragma unroll
        for (int mg = 0; mg < 4; mg++)
        #pragma unroll
        for (int r = 0; r < 4; r++) {
            int row = mg * 16 + kg * 4 + r;
            x2f[row * 132 + n0 + lr] = accp[mg][r] + bn + xres[mg][r];
        }
    }

    // preload fc1 k0=0 B-frags: independent of x2f/zn; hides W1 L2 latency under LN2
    short8 w1f0[4];
    #pragma unroll
    for (int ni = 0; ni < 4; ni++)
        w1f0[ni] = *(const short8*)(W1 + (size_t)(((((wv * 4 + ni) * 4 + 0) * 4 + kg) * 16 + lr)) * 8);
    __syncthreads();

    // ---- LN2 from x2f -> zn (swizzled bf16), concurrent reductions ----
    #pragma unroll
    for (int r = 0; r < 8; r++) {
        int rl = wv * 8 + r;
        float2 v = *(const float2*)&x2f[rl * 132 + lane * 2];
        float s  = v.x + v.y;
        float s2 = v.x * v.x + v.y * v.y;
        #pragma unroll
        for (int o = 32; o > 0; o >>= 1) {
            s  += __shfl_xor(s, o);
            s2 += __shfl_xor(s2, o);
        }
        float mu = s * (1.0f / 128.0f);
        float var = s2 * (1.0f / 128.0f) - mu * mu;
        float rstd = rsqrtf(var + 1e-5f);
        float d0 = v.x - mu, d1 = v.y - mu;
        float2 wv2 = *(const float2*)(lnw + lane * 2);
        float2 bv2 = *(const float2*)(lnb + lane * 2);
        uint pk = f2b(d0 * rstd * wv2.x + bv2.x)
                | (f2b(d1 * rstd * wv2.y + bv2.y) << 16);
        *(uint*)((char*)zn + rl * 256 + ((lane * 4) ^ ((rl & 7) << 4))) = pk;
    }
    __syncthreads();

    // ---- fc1 + GELU single pass: wave owns cols [wv*64, +64), ngrp = wv*4+ni ----
    {
        f32x4 acc1[4][4] = {};
        int nc0 = wv * 64;
        #pragma unroll
        for (int k0 = 0; k0 < 128; k0 += 32) {
            short8 bf[4];
            #pragma unroll
            for (int ni = 0; ni < 4; ni++)
                bf[ni] = (k0 == 0) ? w1f0[ni]
                       : *(const short8*)(W1 + (size_t)(((((wv * 4 + ni) * 4 + (k0 >> 5)) * 4 + kg) * 16 + lr)) * 8);
            #pragma unroll
            for (int mg = 0; mg < 4; mg++) {
                int row = mg * 16 + lr;
                short8 a0 = *(const short8*)((char*)zn + row * 256 + ((k0 * 2 + kg * 16) ^ ((row & 7) << 4)));
                #pragma unroll
                for (int ni = 0; ni < 4; ni++)
                    acc1[mg][ni] = __builtin_amdgcn_mfma_f32_16x16x32_bf16(a0, bf[ni], acc1[mg][ni], 0, 0, 0);
            }
        }
        #pragma unroll
        for (int mg = 0; mg < 4; mg++)
        #pragma unroll
        for (int ni = 0; ni < 4; ni++) {
            int lc = nc0 + ni * 16 + lr;
            float bn = b1[lc];
            #pragma unroll
            for (int r = 0; r < 4; r++) {
                int row = mg * 16 + kg * 4 + r;
                float v = acc1[mg][ni][r] + bn;
                // sigmoid-form tanh GELU (max dev ~3e-4 vs exact erf)
                float t = v + 0.044715f * v * v * v;
                float sg = 1.0f / (1.0f + __expf(-1.5957691216f * t));
                v = v * sg;
                *(ushort*)((char*)hb + row * 1024 + ((lc * 2) ^ ((row & 7) << 4))) = (ushort)f2b(v);
            }
        }
    }
    __syncthreads();

    // ---- fc2: unbroken K = 512 loop from hb; ngrp = (wv&3)*2+ni ----
    int rw0 = (wv >> 2) * 32, cw0 = (wv & 3) * 32;   // fc2 wave tile 32x32
    f32x4 acc2[2][2] = {};
    #pragma unroll
    for (int k0 = 0; k0 < 512; k0 += 32) {
        short8 a0[2], bf[2];
        #pragma unroll
        for (int mi = 0; mi < 2; mi++) {
            int row = rw0 + mi * 16 + lr;
            a0[mi] = *(const short8*)((char*)hb + row * 1024 + ((k0 * 2 + kg * 16) ^ ((row & 7) << 4)));
        }
        #pragma unroll
        for (int ni = 0; ni < 2; ni++)
            bf[ni] = *(const short8*)(W2 + (size_t)((((((wv & 3) * 2 + ni) * 16 + (k0 >> 5)) * 4 + kg) * 16 + lr)) * 8);
        #pragma unroll
        for (int mi = 0; mi < 2; mi++)
        #pragma unroll
        for (int ni = 0; ni < 2; ni++)
            acc2[mi][ni] = __builtin_amdgcn_mfma_f32_16x16x32_bf16(a0[mi], bf[ni], acc2[mi][ni], 0, 0, 0);
    }

    #pragma unroll
    for (int mi = 0; mi < 2; mi++)
    #pragma unroll
    for (int ni = 0; ni < 2; ni++) {
        int col = cw0 + ni * 16 + lr;
        float bn = b2[col];
        #pragma unroll
        for (int r = 0; r < 4; r++) {
            int row = rw0 + mi * 16 + kg * 4 + r;
            out[(size_t)(m0 + row) * CDIM + col] = acc2[mi][ni][r] + bn + x2f[row * 132 + col];
        }
    }
}

// ---------- Neighborhood attention v9 (R18-validated): ks stride-40, hoisted Q ----------
__global__ __launch_bounds__(256) void nat_attn9(const ushort* __restrict__ qkv,
                                                 const float* __restrict__ rpb,
                                                 ushort* __restrict__ ao) {
    __shared__ ushort katt[8704];      // union: ks[208*40]=8320 (scores) / att 4x16x136
    __shared__ ushort vs[32 * 232];
    __shared__ float rpl[169];
    ushort* ks = katt;

    int tid = threadIdx.x, wv = tid >> 6, lane = tid & 63;
    int lr = lane & 15, kg = lane >> 4;
    int bid = blockIdx.x;
    int blk = (bid & 7) * 98 + (bid >> 3);   // bijective XCD chunking (784 = 8*98)
    int tile = blk % 49, hb2 = blk / 49;
    int head = hb2 & 3, b = hb2 >> 2;
    int r0 = (tile / 7) * 8, c0 = (tile % 7) * 8;
    int hr0 = min(max(r0 - 3, 0), HSZ - 14);
    int hc0 = min(max(c0 - 3, 0), WSZ - 14);
    int bimg = b * HSZ * WSZ;

    const ushort* qb = qkv + (size_t)(0 + head) * TOK * HD;
    const ushort* kb = qkv + (size_t)(4 + head) * TOK * HD;
    const ushort* vb = qkv + (size_t)(8 + head) * TOK * HD;

    // hoisted Q-frag load: issues alongside staging loads
    int apix = wv * 16 + lr;
    int agp = bimg + (r0 + 2 * wv + ((apix & 15) >> 3)) * WSZ + c0 + (apix & 7);
    short8 aq = *(const short8*)(qb + (size_t)agp * HD + kg * 8);

    if (tid < 169) rpl[tid] = rpb[head * 169 + tid];
    for (int idx = tid; idx < 784; idx += 256) {
        int t = idx >> 2, c = idx & 3;
        int gtok = bimg + (hr0 + t / 14) * WSZ + hc0 + t % 14;
        short8 v = *(const short8*)(kb + (size_t)gtok * HD + c * 8);
        *(short8*)(ks + t * 40 + c * 8) = v;
    }
    for (int idx = tid; idx < 392; idx += 256) {
        int pr = idx >> 2, c = idx & 3;
        int t = pr * 2;
        int gtok = bimg + (hr0 + t / 14) * WSZ + hc0 + t % 14;
        const ushort* vp = vb + (size_t)gtok * HD + c * 8;
        short8 v0 = *(const short8*)vp;
        short8 v1 = *(const short8*)(vp + HD);
        #pragma unroll
        for (int q = 0; q < 8; q++)
            *(uint*)(vs + (c * 8 + q) * 232 + t) =
                (uint)(ushort)v0[q] | ((uint)(ushort)v1[q] << 16);
    }
    for (int idx = tid; idx < 32 * 18; idx += 256)
        *(uint*)(vs + (idx / 18) * 232 + 196 + (idx % 18) * 2) = 0;
    __syncthreads();

    int i0 = r0 + 2 * wv;
    int hw0 = min(max(i0 - 3, 0), HSZ - KS);
    int dwr = hw0 - hr0;
    int tbase = dwr * 14;
    int rb = tbase & ~7;
    int rboff = tbase - rb;                  // even, in {0,2,4,6}

    f32x4 sc[7];
    #pragma unroll
    for (int tl = 0; tl < 7; tl++) {
        int t = tbase + tl * 16 + lr;
        short8 bk = *(const short8*)(ks + t * 40 + kg * 8);
        f32x4 z = {0.f, 0.f, 0.f, 0.f};
        sc[tl] = __builtin_amdgcn_mfma_f32_16x16x32_bf16(aq, bk, z, 0, 0, 0);
    }
    __syncthreads();   // all ks reads done before att overwrites the union

    ushort* attw = katt + wv * 16 * 136;
    #pragma unroll
    for (int z = 0; z < 2; z++) {
        int ii = z * 64 + lane;              // 0..127 pad-uints (16 rows x 8)
        int row = ii >> 3, c2 = (ii & 7) * 2;
        int col = c2 + (c2 < rboff ? 0 : 112);
        *(uint*)(attw + row * 136 + col) = 0;
    }

    float inv[4];
    #pragma unroll
    for (int r = 0; r < 4; r++) {
        int idx = kg * 4 + r;
        int i = r0 + 2 * wv + (idx >> 3), j = c0 + (idx & 7);
        int shh = min(max(i - 3, 0), HSZ - KS);
        int sww = min(max(j - 3, 0), WSZ - KS);
        int dih = shh - hr0, dj = sww - hc0;
        int offh = hr0 - i + 6, offw = hc0 - j + 6;
        float sum = 0.f;
        #pragma unroll
        for (int tl = 0; tl < 7; tl++) {
            int t = tbase + tl * 16 + lr;
            int thr = (unsigned)t / 14u;
            int twr = t - thr * 14;
            bool in = ((unsigned)(thr - dih) < 7u) && ((unsigned)(twr - dj) < 7u);
            int bidx = (thr + offh) * 13 + (twr + offw);
            bidx = min(max(bidx, 0), 168);
            float e = in ? __expf(sc[tl][r] + rpl[bidx]) : 0.f;
            sum += e;
            attw[idx * 136 + rboff + tl * 16 + lr] = (ushort)f2b(e);
        }
        #pragma unroll
        for (int o = 8; o > 0; o >>= 1) sum += __shfl_xor(sum, o);
        inv[r] = 1.0f / sum;
    }

    f32x4 po[2] = {};
    #pragma unroll
    for (int kst = 0; kst < 4; kst++) {
        short8 pa = *(const short8*)(attw + lr * 136 + kst * 32 + kg * 8);
        #pragma unroll
        for (int n = 0; n < 2; n++) {
            short8 vbf = *(const short8*)(vs + (n * 16 + lr) * 232 + rb + kst * 32 + kg * 8);
            po[n] = __builtin_amdgcn_mfma_f32_16x16x32_bf16(pa, vbf, po[n], 0, 0, 0);
        }
    }

    #pragma unroll
    for (int n = 0; n < 2; n++)
    #pragma unroll
    for (int rr = 0; rr < 4; rr++) {
        int idx = kg * 4 + rr;
        int gp = bimg + (r0 + 2 * wv + (idx >> 3)) * WSZ + c0 + (idx & 7);
        ao[(size_t)gp * CDIM + head * HD + n * 16 + lr] = (ushort)f2b(po[n][rr] * inv[rr]);
    }
}

extern "C" void kernel_launch(void* const* d_in, const int* in_sizes, int n_in,
                              void* d_out, int out_size, void* d_ws, size_t ws_size,
                              hipStream_t stream) {
    const float* x      = (const float*)d_in[0];
    const float* n1w    = (const float*)d_in[1];
    const float* n1b    = (const float*)d_in[2];
    const float* qkv_w  = (const float*)d_in[3];
    const float* qkv_b  = (const float*)d_in[4];
    const float* rpb    = (const float*)d_in[5];
    const float* proj_w = (const float*)d_in[6];
    const float* proj_b = (const float*)d_in[7];
    const float* n2w    = (const float*)d_in[8];
    const float* n2b    = (const float*)d_in[9];
    const float* fc1_w  = (const float*)d_in[10];
    const float* fc1_b  = (const float*)d_in[11];
    const float* fc2_w  = (const float*)d_in[12];
    const float* fc2_b  = (const float*)d_in[13];
    float* out = (float*)d_out;

    ushort* wb   = (ushort*)d_ws;                        // 196608 bf16 weights (frag order)
    ushort* qkvb = wb + 196608;                          // [3][4][TOK][32] bf16
    ushort* aob  = qkvb + (size_t)TOK * 384;             // TOK*128 bf16

    const ushort* w_qkv  = wb;
    const ushort* w_proj = wb + 49152;
    const ushort* w_fc1  = wb + 65536;
    const ushort* w_fc2  = wb + 131072;

    convert_w<<<96, 256, 0, stream>>>(qkv_w, proj_w, fc1_w, fc2_w, wb);
    ln1_qkv<<<TOK / 64, 512, 0, stream>>>(x, w_qkv, qkv_b, n1w, n1b, qkvb);
    nat_attn9<<<4 * NHEAD * 49, 256, 0, stream>>>(qkvb, rpb, aob);
    proj_mlp<<<TOK / 64, 512, 0, stream>>>(aob, w_proj, proj_b, x,
                                           w_fc1, fc1_b, w_fc2, fc2_b, n2w, n2b, out);
}